// Round 1
// baseline (29.626 us; speedup 1.0000x reference)
//
#include <hip/hip_runtime.h>
#include <hip/hip_bf16.h>

// Constants from the reference
#define E_DIM 16
#define H_DIM 8
#define DI 8
#define DO 8
#define F_DIM 48
#define L_IN (F_DIM * DI)   // 384
#define L_OUT (F_DIM * DO)  // 384
#define SZ_B 4

// out[bh, l, m] = sum_d q[bh,l,d] * ( r_voice[l%8, m%8, d, h] + rt(l/8, m/8, d, h) )
//   rt(fp,fq,d,h) = fp >= fq ? e_past[fp-fq,d,h] : e_future[fq-fp,d,h]
// Per row (bh,l): 8 voice dots V[m%8] + 48 time dots T[m/8]; out = V + T broadcast.
__global__ __launch_bounds__(64)
void bsa_row_kernel(const float* __restrict__ q,
                    const float* __restrict__ r_voice,
                    const float* __restrict__ e_past,
                    const float* __restrict__ e_future,
                    float* __restrict__ out) {
    const int l    = blockIdx.x;          // [0, 384)
    const int bh   = blockIdx.y;          // [0, 32)
    const int h    = bh & (H_DIM - 1);
    const int lane = threadIdx.x;         // [0, 64)
    const int vi   = l & (DI - 1);
    const int fi   = l >> 3;

    __shared__ float qrow[E_DIM];
    __shared__ float T[F_DIM];
    __shared__ float V[DO];

    if (lane < E_DIM)
        qrow[lane] = q[((size_t)bh * L_IN + l) * E_DIM + lane];
    __syncthreads();

    if (lane < F_DIM) {
        const int fq = lane;
        const float* tab = (fi >= fq)
            ? (e_past   + (size_t)(fi - fq) * E_DIM * H_DIM)
            : (e_future + (size_t)(fq - fi) * E_DIM * H_DIM);
        float s = 0.f;
        #pragma unroll
        for (int d = 0; d < E_DIM; ++d)
            s += qrow[d] * tab[d * H_DIM + h];
        T[fq] = s;
    } else if (lane < F_DIM + DO) {
        const int vj = lane - F_DIM;
        const float* tab = r_voice + (size_t)(vi * DO + vj) * E_DIM * H_DIM;
        float s = 0.f;
        #pragma unroll
        for (int d = 0; d < E_DIM; ++d)
            s += qrow[d] * tab[d * H_DIM + h];
        V[vj] = s;
    }
    __syncthreads();

    float* orow = out + ((size_t)bh * L_IN + l) * L_OUT;
    #pragma unroll
    for (int k = 0; k < 3; ++k) {
        const int j = k * 128 + lane * 2;
        float2 v;
        v.x = T[j >> 3]       + V[j & 7];
        v.y = T[(j + 1) >> 3] + V[(j + 1) & 7];
        *reinterpret_cast<float2*>(orow + j) = v;
    }
}

extern "C" void kernel_launch(void* const* d_in, const int* in_sizes, int n_in,
                              void* d_out, int out_size, void* d_ws, size_t ws_size,
                              hipStream_t stream) {
    const float* q        = (const float*)d_in[0];
    // d_in[1] = flipped_masks (unused)
    const float* r_voice  = (const float*)d_in[2];
    const float* e_past   = (const float*)d_in[3];
    const float* e_future = (const float*)d_in[4];
    float* out = (float*)d_out;

    dim3 grid(L_IN, SZ_B * H_DIM);  // (384, 32)
    dim3 block(64);
    bsa_row_kernel<<<grid, block, 0, stream>>>(q, r_voice, e_past, e_future, out);
}

// Round 2
// 27.698 us; speedup vs baseline: 1.0696x; 1.0696x over previous
//
#include <hip/hip_runtime.h>
#include <hip/hip_bf16.h>

// Constants from the reference
#define E_DIM 16
#define H_DIM 8
#define DI 8
#define DO 8
#define F_DIM 48
#define L_IN (F_DIM * DI)   // 384
#define L_OUT (F_DIM * DO)  // 384
#define SZ_B 4

// out[bh, l, m] = sum_d q[bh,l,d] * ( r_voice[l%8, m%8, d, h] + rt(l/8, m/8, d, h) )
//   rt(fp,fq,d,h) = fp >= fq ? e_past[fp-fq,d,h] : e_future[fq-fp,d,h]
// Block = (fi, bh): 8 rows l = fi*8 + vi. Row decomposes as T[vi][m>>3] + V[vi][m&7].
__global__ __launch_bounds__(256)
void bsa_block_kernel(const float* __restrict__ q,
                      const float* __restrict__ r_voice,
                      const float* __restrict__ e_past,
                      const float* __restrict__ e_future,
                      float* __restrict__ out) {
    const int fi = blockIdx.x;    // [0, 48)
    const int bh = blockIdx.y;    // [0, 32)
    const int h  = bh & (H_DIM - 1);
    const int t  = threadIdx.x;   // [0, 256)

    __shared__ float qrows[DI][E_DIM];   // 8 x 16
    __shared__ float Trow[DI][F_DIM];    // 8 x 48
    __shared__ float Vrow[DI][DO];       // 8 x 8

    // Stage 8 q-rows (128 floats)
    if (t < DI * E_DIM) {
        const int vi = t >> 4, d = t & 15;
        qrows[vi][d] = q[((size_t)bh * L_IN + fi * DI + vi) * E_DIM + d];
    }
    __syncthreads();

    // 448 dots: 384 time (vi,fq) + 64 voice (vi,vj); <=2 per thread
    for (int dot = t; dot < 448; dot += 256) {
        if (dot < 384) {
            const int vi = dot / F_DIM;
            const int fq = dot - vi * F_DIM;
            const float* tab = (fi >= fq)
                ? (e_past   + (size_t)(fi - fq) * E_DIM * H_DIM)
                : (e_future + (size_t)(fq - fi) * E_DIM * H_DIM);
            float s = 0.f;
            #pragma unroll
            for (int d = 0; d < E_DIM; ++d)
                s += qrows[vi][d] * tab[d * H_DIM + h];
            Trow[vi][fq] = s;
        } else {
            const int r  = dot - 384;
            const int vi = r >> 3, vj = r & 7;
            const float* tab = r_voice + (size_t)(vi * DO + vj) * E_DIM * H_DIM;
            float s = 0.f;
            #pragma unroll
            for (int d = 0; d < E_DIM; ++d)
                s += qrows[vi][d] * tab[d * H_DIM + h];
            Vrow[vi][vj] = s;
        }
    }
    __syncthreads();

    // Write 8 rows x 384 floats = 3072 floats = 3 iters x 256 threads x float4
    float* obase = out + ((size_t)bh * L_IN + fi * DI) * L_OUT;
    #pragma unroll
    for (int it = 0; it < 3; ++it) {
        const int f  = it * 1024 + t * 4;       // [0, 3072), multiple of 4
        const int vi = f / L_OUT;               // row within block
        const int m  = f - vi * L_OUT;          // [0, 384), multiple of 4
        const int mf = m >> 3;
        const int mv = m & 7;                   // 0 or 4
        const float tval = Trow[vi][mf];
        float4 v;
        v.x = tval + Vrow[vi][mv + 0];
        v.y = tval + Vrow[vi][mv + 1];
        v.z = tval + Vrow[vi][mv + 2];
        v.w = tval + Vrow[vi][mv + 3];
        *reinterpret_cast<float4*>(obase + f) = v;
    }
}

extern "C" void kernel_launch(void* const* d_in, const int* in_sizes, int n_in,
                              void* d_out, int out_size, void* d_ws, size_t ws_size,
                              hipStream_t stream) {
    const float* q        = (const float*)d_in[0];
    // d_in[1] = flipped_masks (unused)
    const float* r_voice  = (const float*)d_in[2];
    const float* e_past   = (const float*)d_in[3];
    const float* e_future = (const float*)d_in[4];
    float* out = (float*)d_out;

    dim3 grid(F_DIM, SZ_B * H_DIM);  // (48, 32)
    dim3 block(256);
    bsa_block_kernel<<<grid, block, 0, stream>>>(q, r_voice, e_past, e_future, out);
}

// Round 3
// 17.076 us; speedup vs baseline: 1.7349x; 1.6221x over previous
//
#include <hip/hip_runtime.h>
#include <hip/hip_bf16.h>

// Constants from the reference
#define E_DIM 16
#define H_DIM 8
#define DI 8
#define DO 8
#define F_DIM 48
#define L_IN (F_DIM * DI)   // 384
#define L_OUT (F_DIM * DO)  // 384
#define SZ_B 4

// Workspace layout (floats):
//   TPt[8][48][16]  @ 0      : e_past  transposed to [h][f][d]
//   TFt[8][48][16]  @ 6144   : e_future transposed
//   RVt[8][64][16]  @ 12288  : r_voice transposed to [h][vi*8+vj][d]
#define TP_OFF 0
#define TF_OFF 6144
#define RV_OFF 12288
#define WS_FLOATS 20480

__global__ __launch_bounds__(256)
void bsa_transpose_kernel(const float* __restrict__ e_past,
                          const float* __restrict__ e_future,
                          const float* __restrict__ r_voice,
                          float* __restrict__ ws) {
    const int idx = blockIdx.x * 256 + threadIdx.x;   // [0, 20480)
    if (idx < 6144) {
        // TPt[h][f][d] = e_past[f][d][h]
        const int h = idx >> 9;            // /768? no: 6144/8=768 per h -> idx/768
        const int hh = idx / 768;
        (void)h;
        const int rem = idx - hh * 768;
        const int f = rem >> 4, d = rem & 15;
        ws[TP_OFF + idx] = e_past[(f * 16 + d) * 8 + hh];
    } else if (idx < 12288) {
        const int j = idx - 6144;
        const int hh = j / 768;
        const int rem = j - hh * 768;
        const int f = rem >> 4, d = rem & 15;
        ws[TF_OFF + j] = e_future[(f * 16 + d) * 8 + hh];
    } else {
        const int j = idx - 12288;         // [0, 8192)
        const int hh = j >> 10;            // /1024
        const int rem = j & 1023;
        const int r = rem >> 4, d = rem & 15;
        ws[RV_OFF + j] = r_voice[(r * 16 + d) * 8 + hh];
    }
}

// Block = (fi, bh): 8 rows l = fi*8 + vi. out_row = T[vi][m>>3] + V[vi][m&7].
__global__ __launch_bounds__(256)
void bsa_block_kernel(const float* __restrict__ q,
                      const float* __restrict__ ws,
                      float* __restrict__ out) {
    const int fi = blockIdx.x;    // [0, 48)
    const int bh = blockIdx.y;    // [0, 32)
    const int h  = bh & (H_DIM - 1);
    const int t  = threadIdx.x;   // [0, 256)

    __shared__ float tt[F_DIM * 17];     // 48 rows, stride 17 (pad)
    __shared__ float rv[64 * 17];        // 64 rows, stride 17
    __shared__ float qs[DI * E_DIM];     // 8 x 16
    __shared__ float Trow[DI][F_DIM];    // 8 x 48
    __shared__ float Vrow[DI][DO];       // 8 x 8

    // Stage time rows: tt[fq][d] = (fq<=fi ? TPt[h][fi-fq][d] : TFt[h][fq-fi][d])
    for (int i = t; i < F_DIM * E_DIM; i += 256) {
        const int fq = i >> 4, d = i & 15;
        const float v = (fq <= fi)
            ? ws[TP_OFF + (h * F_DIM + (fi - fq)) * E_DIM + d]
            : ws[TF_OFF + (h * F_DIM + (fq - fi)) * E_DIM + d];
        tt[fq * 17 + d] = v;
    }
    // Stage voice rows: rv[r][d] = RVt[h][r][d]
    for (int i = t; i < 64 * E_DIM; i += 256) {
        const int r = i >> 4, d = i & 15;
        rv[r * 17 + d] = ws[RV_OFF + (h * 64 + r) * E_DIM + d];
    }
    // Stage 8 q-rows (128 floats, contiguous)
    if (t < DI * E_DIM)
        qs[t] = q[((size_t)bh * L_IN + fi * DI) * E_DIM + t];
    __syncthreads();

    // 448 dots from LDS only
    for (int dot = t; dot < 448; dot += 256) {
        float s = 0.f;
        if (dot < 384) {
            const int vi = dot / F_DIM;
            const int fq = dot - vi * F_DIM;
            #pragma unroll
            for (int d = 0; d < E_DIM; ++d)
                s += qs[vi * E_DIM + d] * tt[fq * 17 + d];
            Trow[vi][fq] = s;
        } else {
            const int r  = dot - 384;
            const int vi = r >> 3;
            #pragma unroll
            for (int d = 0; d < E_DIM; ++d)
                s += qs[vi * E_DIM + d] * rv[r * 17 + d];
            Vrow[vi][r & 7] = s;
        }
    }
    __syncthreads();

    // Write 8 rows x 384 floats = 3072 floats = 3 iters x 256 threads x float4
    float* obase = out + ((size_t)bh * L_IN + fi * DI) * L_OUT;
    #pragma unroll
    for (int it = 0; it < 3; ++it) {
        const int f  = it * 1024 + t * 4;       // [0, 3072), multiple of 4
        const int vi = f / L_OUT;
        const int m  = f - vi * L_OUT;
        const int mf = m >> 3;
        const int mv = m & 7;                   // 0 or 4
        const float tval = Trow[vi][mf];
        float4 v;
        v.x = tval + Vrow[vi][mv + 0];
        v.y = tval + Vrow[vi][mv + 1];
        v.z = tval + Vrow[vi][mv + 2];
        v.w = tval + Vrow[vi][mv + 3];
        *reinterpret_cast<float4*>(obase + f) = v;
    }
}

extern "C" void kernel_launch(void* const* d_in, const int* in_sizes, int n_in,
                              void* d_out, int out_size, void* d_ws, size_t ws_size,
                              hipStream_t stream) {
    const float* q        = (const float*)d_in[0];
    // d_in[1] = flipped_masks (unused)
    const float* r_voice  = (const float*)d_in[2];
    const float* e_past   = (const float*)d_in[3];
    const float* e_future = (const float*)d_in[4];
    float* ws  = (float*)d_ws;
    float* out = (float*)d_out;

    bsa_transpose_kernel<<<dim3(WS_FLOATS / 256), dim3(256), 0, stream>>>(
        e_past, e_future, r_voice, ws);

    dim3 grid(F_DIM, SZ_B * H_DIM);  // (48, 32)
    bsa_block_kernel<<<grid, dim3(256), 0, stream>>>(q, ws, out);
}

// Round 5
// 14.120 us; speedup vs baseline: 2.0982x; 1.2094x over previous
//
#include <hip/hip_runtime.h>
#include <hip/hip_bf16.h>

// Constants from the reference
#define E_DIM 16
#define H_DIM 8
#define DI 8
#define DO 8
#define F_DIM 48
#define L_IN (F_DIM * DI)   // 384
#define L_OUT (F_DIM * DO)  // 384
#define SZ_B 4

typedef float f32x4 __attribute__((ext_vector_type(4)));

// out[bh, l, m] = sum_d q[bh,l,d] * ( r_voice[l%8, m%8, d, h] + rt(l/8, m/8, d, h) )
//   rt(fp,fq,d,h) = fp >= fq ? e_past[fp-fq,d,h] : e_future[fq-fp,d,h]
// Single fused kernel. Block = (fi, bh): rows l = fi*8 + vi.
// Phase 1: gather-stage transposed table slices (this block's h-plane) into LDS.
// Phase 2: 448 dots (8x48 time + 8x8 voice) from LDS.
// Phase 3: expand + coalesced nontemporal float4 stores (12 KB/block).
__global__ __launch_bounds__(256)
void bsa_fused_kernel(const float* __restrict__ q,
                      const float* __restrict__ r_voice,
                      const float* __restrict__ e_past,
                      const float* __restrict__ e_future,
                      float* __restrict__ out) {
    const int fi = blockIdx.x;    // [0, 48)
    const int bh = blockIdx.y;    // [0, 32)
    const int h  = bh & (H_DIM - 1);
    const int t  = threadIdx.x;   // [0, 256)

    __shared__ float tt[F_DIM * 17];     // time rows, stride 17 (bank spread)
    __shared__ float rv[64 * 17];        // voice rows, stride 17
    __shared__ float qs[DI * E_DIM];     // 8 x 16
    __shared__ float Trow[DI][F_DIM];    // 8 x 48
    __shared__ float Vrow[DI][DO];       // 8 x 8

    // Stage time rows: tt[fq][d] = (fq<=fi ? e_past[fi-fq][d][h] : e_future[fq-fi][d][h])
    for (int i = t; i < F_DIM * E_DIM; i += 256) {
        const int fq = i >> 4, d = i & 15;
        const float v = (fq <= fi)
            ? e_past  [((size_t)(fi - fq) * E_DIM + d) * H_DIM + h]
            : e_future[((size_t)(fq - fi) * E_DIM + d) * H_DIM + h];
        tt[fq * 17 + d] = v;
    }
    // Stage voice rows: rv[r][d] = r_voice[r][d][h], r = vi*8+vj
    for (int i = t; i < 64 * E_DIM; i += 256) {
        const int r = i >> 4, d = i & 15;
        rv[r * 17 + d] = r_voice[((size_t)r * E_DIM + d) * H_DIM + h];
    }
    // Stage 8 q-rows (128 floats, contiguous coalesced)
    if (t < DI * E_DIM)
        qs[t] = q[((size_t)bh * L_IN + fi * DI) * E_DIM + t];
    __syncthreads();

    // 448 dots from LDS only
    for (int dot = t; dot < 448; dot += 256) {
        float s = 0.f;
        if (dot < 384) {
            const int vi = dot / F_DIM;
            const int fq = dot - vi * F_DIM;
            #pragma unroll
            for (int d = 0; d < E_DIM; ++d)
                s += qs[vi * E_DIM + d] * tt[fq * 17 + d];
            Trow[vi][fq] = s;
        } else {
            const int r  = dot - 384;
            const int vi = r >> 3;
            #pragma unroll
            for (int d = 0; d < E_DIM; ++d)
                s += qs[vi * E_DIM + d] * rv[r * 17 + d];
            Vrow[vi][r & 7] = s;
        }
    }
    __syncthreads();

    // Write 8 rows x 384 floats = 3072 floats = 3 iters x 256 threads x float4
    float* obase = out + ((size_t)bh * L_IN + fi * DI) * L_OUT;
    #pragma unroll
    for (int it = 0; it < 3; ++it) {
        const int f  = it * 1024 + t * 4;       // [0, 3072), multiple of 4
        const int vi = f / L_OUT;
        const int m  = f - vi * L_OUT;
        const int mf = m >> 3;
        const int mv = m & 7;                   // 0 or 4
        const float tval = Trow[vi][mf];
        f32x4 v;
        v.x = tval + Vrow[vi][mv + 0];
        v.y = tval + Vrow[vi][mv + 1];
        v.z = tval + Vrow[vi][mv + 2];
        v.w = tval + Vrow[vi][mv + 3];
        __builtin_nontemporal_store(v, reinterpret_cast<f32x4*>(obase + f));
    }
}

extern "C" void kernel_launch(void* const* d_in, const int* in_sizes, int n_in,
                              void* d_out, int out_size, void* d_ws, size_t ws_size,
                              hipStream_t stream) {
    const float* q        = (const float*)d_in[0];
    // d_in[1] = flipped_masks (unused)
    const float* r_voice  = (const float*)d_in[2];
    const float* e_past   = (const float*)d_in[3];
    const float* e_future = (const float*)d_in[4];
    float* out = (float*)d_out;

    dim3 grid(F_DIM, SZ_B * H_DIM);  // (48, 32)
    bsa_fused_kernel<<<grid, dim3(256), 0, stream>>>(q, r_voice, e_past, e_future, out);
}

// Round 6
// 10.668 us; speedup vs baseline: 2.7772x; 1.3236x over previous
//
#include <hip/hip_runtime.h>
#include <hip/hip_bf16.h>

// Constants from the reference
#define E_DIM 16
#define H_DIM 8
#define F_DIM 48
#define L_IN 384
#define L_OUT 384
#define SZ_B 4

#define NCHUNK 8            // fi-chunks per bh
#define ROWS_PER_BLOCK 48   // 6 fi * 8 vi
#define FI_PER 6
#define TSTRIDE 20          // padded table row stride (floats): 80 B, 16B-aligned b128 rows

typedef float f32x4 __attribute__((ext_vector_type(4)));

// out[bh, l, m] = sum_d q[bh,l,d] * ( r_voice[l%8, m%8, d, h] + rt(l/8, m/8, d, h) )
//   rt(fp,fq,d,h) = fp>=fq ? e_past[fp-fq,d,h] : e_future[fq-fp,d,h]
// Block = (chunk, bh): 48 rows l = chunk*48 + lrow. Full tables staged ONCE
// (fi-independent, indexed by |fi-fq| at dot time), then 8 waves work
// independently: wave w owns rows w*6..w*6+5.
__global__ __launch_bounds__(512)
void bsa_fused_kernel(const float* __restrict__ q,
                      const float* __restrict__ r_voice,
                      const float* __restrict__ e_past,
                      const float* __restrict__ e_future,
                      float* __restrict__ out) {
    const int chunk = blockIdx.x;   // [0, 8)
    const int bh    = blockIdx.y;   // [0, 32)
    const int h     = bh & (H_DIM - 1);
    const int t     = threadIdx.x;  // [0, 512)
    const int w     = t >> 6;
    const int lane  = t & 63;

    // Table rows (stride TSTRIDE): 0..47 = past[diff], 48..95 = future[diff], 96..159 = voice[vi*8+vj]
    __shared__ __attribute__((aligned(16))) float tabs[160 * TSTRIDE];  // 12.8 KB
    __shared__ __attribute__((aligned(16))) float qs[ROWS_PER_BLOCK * E_DIM]; // 3 KB
    __shared__ __attribute__((aligned(16))) float scratch[8 * 64];      // per-wave row results

    // Stage transposed tables (one h-plane). i = f*16+d; flat src = i*8+h.
    for (int i = t; i < F_DIM * E_DIM; i += 512) {
        const int f = i >> 4, d = i & 15;
        tabs[f * TSTRIDE + d]           = e_past [(size_t)i * H_DIM + h];
        tabs[(F_DIM + f) * TSTRIDE + d] = e_future[(size_t)i * H_DIM + h];
    }
    for (int i = t; i < 64 * E_DIM; i += 512) {
        const int r = i >> 4, d = i & 15;
        tabs[(96 + r) * TSTRIDE + d] = r_voice[(size_t)i * H_DIM + h];
    }
    // Stage this block's 48 q-rows (contiguous, coalesced)
    for (int i = t; i < ROWS_PER_BLOCK * E_DIM; i += 512)
        qs[i] = q[((size_t)bh * L_IN + chunk * ROWS_PER_BLOCK) * E_DIM + i];
    __syncthreads();

    float* wscratch = &scratch[w * 64];

    for (int j = 0; j < FI_PER; ++j) {
        const int lrow = w * FI_PER + j;      // [0, 48)
        const int l    = chunk * ROWS_PER_BLOCK + lrow;
        const int fi   = l >> 3;
        const int vi   = l & 7;

        // ---- dot phase: lane k<48 -> T[k]; lanes 48..55 -> V[k-48] ----
        int r;
        if (lane < 48) {
            r = (lane <= fi) ? (fi - lane) : (F_DIM + lane - fi);
        } else {
            int vj = (lane - 48) & 7;         // clamp lanes 56..63 to valid rows
            r = 96 + vi * 8 + vj;
        }
        const f32x4* qv = (const f32x4*)&qs[lrow * E_DIM];
        const f32x4* tv = (const f32x4*)&tabs[r * TSTRIDE];
        f32x4 acc = qv[0] * tv[0] + qv[1] * tv[1] + qv[2] * tv[2] + qv[3] * tv[3];
        const float s = acc.x + acc.y + acc.z + acc.w;
        if (lane < 56) wscratch[lane] = s;
        // Same-wave LDS pipe is in-order; fence stops compiler reordering.
        asm volatile("s_waitcnt lgkmcnt(0)" ::: "memory");
        __builtin_amdgcn_wave_barrier();

        // ---- write phase: 96 float4 (384 floats), lanes cover 64 + 32 ----
        float* orow = out + ((size_t)bh * L_IN + l) * L_OUT;
        #pragma unroll
        for (int rr = 0; rr < 2; ++rr) {
            const int jj = rr * 64 + lane;    // vec4 index [0, 96)
            if (jj < 96) {
                const float tval = wscratch[jj >> 1];           // T[m>>3], m=4*jj
                const f32x4 vv = *(const f32x4*)&wscratch[48 + 4 * (jj & 1)]; // V[m&7 ..]
                f32x4 o;
                o.x = tval + vv.x; o.y = tval + vv.y;
                o.z = tval + vv.z; o.w = tval + vv.w;
                __builtin_nontemporal_store(o, (f32x4*)(orow + 4 * jj));
            }
        }
        __builtin_amdgcn_wave_barrier();
    }
}

extern "C" void kernel_launch(void* const* d_in, const int* in_sizes, int n_in,
                              void* d_out, int out_size, void* d_ws, size_t ws_size,
                              hipStream_t stream) {
    const float* q        = (const float*)d_in[0];
    // d_in[1] = flipped_masks (unused)
    const float* r_voice  = (const float*)d_in[2];
    const float* e_past   = (const float*)d_in[3];
    const float* e_future = (const float*)d_in[4];
    float* out = (float*)d_out;

    dim3 grid(NCHUNK, SZ_B * H_DIM);  // (8, 32) = 256 blocks
    bsa_fused_kernel<<<grid, dim3(512), 0, stream>>>(q, r_voice, e_past, e_future, out);
}